// Round 1
// baseline (117.179 us; speedup 1.0000x reference)
//
#include <hip/hip_runtime.h>

#define NB   6            // batch elements per block
#define NOUT (NB * 169)   // 1014 outputs per block
#define BLK  256

__global__ __launch_bounds__(BLK) void ConeProjection_68642167325009_kernel(
    const float* __restrict__ eyes,
    const float* __restrict__ v,
    const float* __restrict__ R,
    const float* __restrict__ t,
    const float* __restrict__ alpha,
    float* __restrict__ out,
    int B)
{
    __shared__ float c[NB][6];
    const int tid = threadIdx.x;
    const int b0  = blockIdx.x * NB;

    // ---- Phase 1: 6 lanes each build the quadratic-form coefficients ----
    if (tid < NB) {
        const int b = b0 + tid;
        if (b < B) {
            float vx = v[b*3+0], vy = v[b*3+1], vz = v[b*3+2];
            float n  = sqrtf(vx*vx + vy*vy + vz*vz);
            n = fmaxf(n, 1e-14f);
            const float inv = 1.0f / n;
            vx *= inv; vy *= inv; vz *= inv;
            const float a = alpha[b];

            // W rows: w0 = R[:,0], w1 = R[:,1], w2 = t - eyes  (R row-major [3][3])
            const float* Rb = R + (size_t)b * 9;
            const float w0x = Rb[0], w0y = Rb[3], w0z = Rb[6];
            const float w1x = Rb[1], w1y = Rb[4], w1z = Rb[7];
            const float w2x = t[b*3+0] - eyes[b*3+0];
            const float w2y = t[b*3+1] - eyes[b*3+1];
            const float w2z = t[b*3+2] - eyes[b*3+2];

            // sigma[a][c] = (vn.w_a)(vn.w_c) - alpha*(w_a.w_c)  [M = vn vn^T - a I]
            const float d0 = vx*w0x + vy*w0y + vz*w0z;
            const float d1 = vx*w1x + vy*w1y + vz*w1z;
            const float d2 = vx*w2x + vy*w2y + vz*w2z;

            const float s00 = d0*d0 - a*(w0x*w0x + w0y*w0y + w0z*w0z);
            const float s11 = d1*d1 - a*(w1x*w1x + w1y*w1y + w1z*w1z);
            const float s22 = d2*d2 - a*(w2x*w2x + w2y*w2y + w2z*w2z);
            const float s01 = d0*d1 - a*(w0x*w1x + w0y*w1y + w0z*w1z);
            const float s02 = d0*d2 - a*(w0x*w2x + w0y*w2y + w0z*w2z);
            const float s12 = d1*d2 - a*(w1x*w2x + w1y*w2y + w1z*w2z);

            c[tid][0] = s00;
            c[tid][1] = s11;
            c[tid][2] = s22;
            c[tid][3] = 2.0f * s01;
            c[tid][4] = 2.0f * s02;
            c[tid][5] = 2.0f * s12;
        }
    }
    __syncthreads();

    // ---- Phase 2: coalesced flat-index writes of 1014 outputs ----
    const size_t base = (size_t)blockIdx.x * NOUT;
    #pragma unroll
    for (int r = 0; r < 4; ++r) {
        const int local = tid + r * BLK;
        if (local < NOUT) {
            // bl = local / 169 (exact for local < 1014): (local*388)>>16
            const int bl = (local * 388) >> 16;
            const int k  = local - 169 * bl;
            if (b0 + bl < B) {
                // i = k / 13 (exact for k < 169): (k*20165)>>18 ; j = k % 13
                const int i = (k * 20165) >> 18;
                const int j = k - 13 * i;
                const float px = (float)(i - 6) * (1.0f / 6.0f);
                const float py = (float)(j - 6) * (1.0f / 6.0f);
                const float val = c[bl][2]
                                + px * (c[bl][0] * px + c[bl][3] * py + c[bl][4])
                                + py * (c[bl][1] * py + c[bl][5]);
                out[base + local] = val;
            }
        }
    }
}

extern "C" void kernel_launch(void* const* d_in, const int* in_sizes, int n_in,
                              void* d_out, int out_size, void* d_ws, size_t ws_size,
                              hipStream_t stream) {
    const float* eyes  = (const float*)d_in[0];
    const float* v     = (const float*)d_in[1];
    const float* R     = (const float*)d_in[2];
    const float* t     = (const float*)d_in[3];
    const float* alpha = (const float*)d_in[4];
    float* out = (float*)d_out;

    const int B = in_sizes[4];               // alpha has B elements
    const int grid = (B + NB - 1) / NB;      // 21846 blocks for B=131072

    ConeProjection_68642167325009_kernel<<<grid, BLK, 0, stream>>>(
        eyes, v, R, t, alpha, out, B);
}

// Round 4
// 112.154 us; speedup vs baseline: 1.0448x; 1.0448x over previous
//
#include <hip/hip_runtime.h>

#define BLK 256

// ---------------- Kernel 1: per-batch quadratic-form coefficients ----------------
// c[b] = { s00, s11, s22, 2*s01, 2*s02, 2*s12, 0, 0 }  (8 floats, 2x float4)
__global__ __launch_bounds__(BLK) void cone_coeff_kernel(
    const float* __restrict__ eyes,
    const float* __restrict__ v,
    const float* __restrict__ R,
    const float* __restrict__ t,
    const float* __restrict__ alpha,
    float* __restrict__ c,
    int B)
{
    const int b = blockIdx.x * BLK + threadIdx.x;
    if (b >= B) return;

    float vx = v[b*3+0], vy = v[b*3+1], vz = v[b*3+2];
    float n  = sqrtf(vx*vx + vy*vy + vz*vz);
    n = fmaxf(n, 1e-14f);
    const float inv = 1.0f / n;
    vx *= inv; vy *= inv; vz *= inv;
    const float a = alpha[b];

    // W rows: w0 = R[:,0], w1 = R[:,1], w2 = t - eyes   (R row-major [3][3])
    const float* Rb = R + (size_t)b * 9;
    const float w0x = Rb[0], w0y = Rb[3], w0z = Rb[6];
    const float w1x = Rb[1], w1y = Rb[4], w1z = Rb[7];
    const float w2x = t[b*3+0] - eyes[b*3+0];
    const float w2y = t[b*3+1] - eyes[b*3+1];
    const float w2z = t[b*3+2] - eyes[b*3+2];

    // sigma[a][c] = (vn.w_a)(vn.w_c) - alpha*(w_a.w_c)
    const float d0 = vx*w0x + vy*w0y + vz*w0z;
    const float d1 = vx*w1x + vy*w1y + vz*w1z;
    const float d2 = vx*w2x + vy*w2y + vz*w2z;

    const float s00 = d0*d0 - a*(w0x*w0x + w0y*w0y + w0z*w0z);
    const float s11 = d1*d1 - a*(w1x*w1x + w1y*w1y + w1z*w1z);
    const float s22 = d2*d2 - a*(w2x*w2x + w2y*w2y + w2z*w2z);
    const float s01 = d0*d1 - a*(w0x*w1x + w0y*w1y + w0z*w1z);
    const float s02 = d0*d2 - a*(w0x*w2x + w0y*w2y + w0z*w2z);
    const float s12 = d1*d2 - a*(w1x*w2x + w1y*w2y + w1z*w2z);

    float4* c4 = (float4*)c;
    c4[2*b+0] = make_float4(s00, s11, s22, 2.0f*s01);
    c4[2*b+1] = make_float4(2.0f*s02, 2.0f*s12, 0.0f, 0.0f);
}

// ---------------- Kernel 2: streaming writer (one float4 per thread-iter) ----------------
__global__ __launch_bounds__(BLK) void cone_write_kernel(
    const float* __restrict__ c,
    float* __restrict__ out,
    int total4)
{
    const int stride = gridDim.x * BLK;
    const float4* __restrict__ c4 = (const float4*)c;
    float4* __restrict__ out4 = (float4*)out;

    for (int i = blockIdx.x * BLK + threadIdx.x; i < total4; i += stride) {
        const int n0 = i * 4;
        // b = n0 / 169 exact for n0 < 2^25  (multiplier err*max < 2^38)
        int b = (int)(((unsigned long long)n0 * 1626496491ULL) >> 38);
        int k = n0 - 169 * b;

        float4 lo = c4[2*b+0];   // s00, s11, s22, 2s01
        float4 hi = c4[2*b+1];   // 2s02, 2s12, -, -

        float r[4];
        #pragma unroll
        for (int e = 0; e < 4; ++e) {
            if (k == 169) {      // crossed a batch boundary (rare: 4/169 of iters)
                ++b; k = 0;
                lo = c4[2*b+0];
                hi = c4[2*b+1];
            }
            // iq = k/13 exact for k<169 (e=1); j = k%13
            const int iq = (k * 20165) >> 18;
            const int j  = k - 13 * iq;
            const float px = (float)(iq - 6) * (1.0f / 6.0f);
            const float py = (float)(j  - 6) * (1.0f / 6.0f);
            r[e] = lo.z + px * (lo.x * px + lo.w * py + hi.x)
                        + py * (lo.y * py + hi.y);
            ++k;
        }
        out4[i] = make_float4(r[0], r[1], r[2], r[3]);
    }
}

extern "C" void kernel_launch(void* const* d_in, const int* in_sizes, int n_in,
                              void* d_out, int out_size, void* d_ws, size_t ws_size,
                              hipStream_t stream) {
    const float* eyes  = (const float*)d_in[0];
    const float* v     = (const float*)d_in[1];
    const float* R     = (const float*)d_in[2];
    const float* t     = (const float*)d_in[3];
    const float* alpha = (const float*)d_in[4];
    float* out = (float*)d_out;
    float* c   = (float*)d_ws;               // 8 floats per batch row = 4 MB

    const int B = in_sizes[4];               // alpha has B elements
    const int total4 = out_size / 4;         // out_size = B*169, divisible by 4

    const int grid1 = (B + BLK - 1) / BLK;   // 512 blocks
    cone_coeff_kernel<<<grid1, BLK, 0, stream>>>(eyes, v, R, t, alpha, c, B);

    const int grid2 = 4096;                  // grid-stride streaming writer
    cone_write_kernel<<<grid2, BLK, 0, stream>>>(c, out, total4);
}